// Round 1
// baseline (361.948 us; speedup 1.0000x reference)
//
#include <hip/hip_runtime.h>

#define NB 8
#define N1 8192
#define N2 2048
#define C1 256
#define C2 512
#define CO 768   // C1 + C2

// ---------------------------------------------------------------------------
// Kernel 1: brute-force 3-NN per query point + inverse-distance weights.
// One block = 256 query points of one batch. Key xyz (+|k|^2) staged in LDS.
// Distance formula mirrors the reference exactly: d2 = (qq + kk) - 2*dot,
// with explicit _rn intrinsics to prevent fp-contract differences that could
// flip near-tied neighbor orderings vs the numpy/XLA reference.
// ---------------------------------------------------------------------------
__global__ __launch_bounds__(256) void knn_kernel(
    const float* __restrict__ qxyz,   // (B, 3, N1)
    const float* __restrict__ kxyz,   // (B, 3, N2)
    int*   __restrict__ nn_idx,       // (B*N1*3)
    float* __restrict__ nn_w)         // (B*N1*3)
{
    __shared__ float skx[N2], sky[N2], skz[N2], skk[N2];
    const int b    = blockIdx.x >> 5;   // 32 tiles of 256 points per batch
    const int tile = blockIdx.x & 31;
    const int tid  = threadIdx.x;

    const float* kb = kxyz + (size_t)b * 3 * N2;
    for (int j = tid; j < N2; j += 256) {
        float x = kb[j], y = kb[N2 + j], z = kb[2 * N2 + j];
        skx[j] = x; sky[j] = y; skz[j] = z;
        skk[j] = __fadd_rn(__fadd_rn(__fmul_rn(x, x), __fmul_rn(y, y)),
                           __fmul_rn(z, z));
    }
    __syncthreads();

    const int n = tile * 256 + tid;
    const float* qb = qxyz + (size_t)b * 3 * N1;
    const float qx = qb[n], qy = qb[N1 + n], qz = qb[2 * N1 + n];
    const float qq = __fadd_rn(__fadd_rn(__fmul_rn(qx, qx), __fmul_rn(qy, qy)),
                               __fmul_rn(qz, qz));

    float b0 = 3.4e38f, b1 = 3.4e38f, b2 = 3.4e38f;
    int   i0 = 0, i1 = 0, i2 = 0;

    #pragma unroll 4
    for (int j = 0; j < N2; ++j) {
        float dot = fmaf(skz[j], qz, fmaf(sky[j], qy, __fmul_rn(skx[j], qx)));
        float d2  = __fsub_rn(__fadd_rn(qq, skk[j]), __fmul_rn(2.0f, dot));
        if (d2 < b2) {                       // rare: exec-mask skips most iters
            bool c0 = d2 < b0, c1 = d2 < b1;
            b2 = c1 ? b1 : d2;               i2 = c1 ? i1 : j;
            b1 = c0 ? b0 : (c1 ? d2 : b1);   i1 = c0 ? i0 : (c1 ? j : i1);
            b0 = c0 ? d2 : b0;               i0 = c0 ? j  : i0;
        }
    }

    // weights: mirror reference op order
    float d0f = fmaxf(b0, 1e-10f), d1f = fmaxf(b1, 1e-10f), d2f = fmaxf(b2, 1e-10f);
    float v0 = __fdiv_rn(1.0f, d0f), v1 = __fdiv_rn(1.0f, d1f), v2 = __fdiv_rn(1.0f, d2f);
    float s  = __fadd_rn(__fadd_rn(v0, v1), v2);
    float w0 = __fdiv_rn(v0, s), w1 = __fdiv_rn(v1, s), w2 = __fdiv_rn(v2, s);

    const int p = (b * N1 + n) * 3;
    nn_idx[p] = i0; nn_idx[p + 1] = i1; nn_idx[p + 2] = i2;
    nn_w[p]   = w0; nn_w[p + 1]  = w1; nn_w[p + 2]  = w2;
}

// ---------------------------------------------------------------------------
// Kernel 2: weighted gather-interpolation -> out channels [0, C2).
// Grid 2048 blocks x 256 thr. b = blockIdx & 7 so each XCD works one batch's
// 4 MB key_feature slab (L2-resident gathers). Wave lanes = consecutive n so
// stores are coalesced; 8 c-groups x 4 waves give 8 waves/SIMD for latency
// hiding of the per-lane scalar gathers.
// ---------------------------------------------------------------------------
__global__ __launch_bounds__(256) void interp_kernel(
    const float* __restrict__ kfeat,  // (B, C2, N2)
    const int*   __restrict__ nn_idx,
    const float* __restrict__ nn_w,
    float* __restrict__ out)          // (B, CO, N1)
{
    const int b    = blockIdx.x & 7;          // XCD-aligned batch
    const int rem  = blockIdx.x >> 3;
    const int tile = rem & 31;                // 32 n-tiles of 256
    const int cg   = rem >> 5;                // 8 channel groups of 64
    const int n    = tile * 256 + threadIdx.x;

    const int p = (b * N1 + n) * 3;
    const int i0 = nn_idx[p], i1 = nn_idx[p + 1], i2 = nn_idx[p + 2];
    const float w0 = nn_w[p], w1 = nn_w[p + 1], w2 = nn_w[p + 2];

    const float* kf = kfeat + (size_t)b * C2 * N2;
    float* ob = out + (size_t)b * CO * N1;

    const int c_lo = cg * 64, c_hi = c_lo + 64;
    #pragma unroll 4
    for (int c = c_lo; c < c_hi; ++c) {
        const float* row = kf + (size_t)c * N2;
        float f0 = row[i0], f1 = row[i1], f2 = row[i2];
        float acc = fmaf(w2, f2, fmaf(w1, f1, __fmul_rn(w0, f0)));
        ob[(size_t)c * N1 + n] = acc;
    }
}

// ---------------------------------------------------------------------------
// Kernel 3: copy query_feature -> out channels [C2, CO). Pure float4 stream.
// Per batch the destination region is contiguous.
// ---------------------------------------------------------------------------
__global__ __launch_bounds__(256) void copy_kernel(
    const float* __restrict__ qfeat,  // (B, C1, N1)
    float* __restrict__ out)          // (B, CO, N1)
{
    // 2048 blocks per batch, each thread moves one float4
    const int b = blockIdx.x >> 11;
    const size_t r = ((size_t)(blockIdx.x & 2047)) * 256 + threadIdx.x; // float4 idx
    const float4* src = (const float4*)(qfeat + (size_t)b * C1 * N1);
    float4* dst = (float4*)(out + (size_t)b * CO * N1 + (size_t)C2 * N1);
    dst[r] = src[r];
}

extern "C" void kernel_launch(void* const* d_in, const int* in_sizes, int n_in,
                              void* d_out, int out_size, void* d_ws, size_t ws_size,
                              hipStream_t stream) {
    const float* qxyz  = (const float*)d_in[0];
    const float* kxyz  = (const float*)d_in[1];
    const float* qfeat = (const float*)d_in[2];
    const float* kfeat = (const float*)d_in[3];
    float* out = (float*)d_out;

    int*   nn_idx = (int*)d_ws;                              // 3*B*N1 ints
    float* nn_w   = (float*)d_ws + (size_t)3 * NB * N1;      // 3*B*N1 floats

    knn_kernel<<<NB * (N1 / 256), 256, 0, stream>>>(qxyz, kxyz, nn_idx, nn_w);
    interp_kernel<<<NB * (N1 / 256) * 8, 256, 0, stream>>>(kfeat, nn_idx, nn_w, out);
    copy_kernel<<<NB * 2048, 256, 0, stream>>>(qfeat, out);
}

// Round 5
// 230.937 us; speedup vs baseline: 1.5673x; 1.5673x over previous
//
#include <hip/hip_runtime.h>

#define NB 8
#define N1 8192
#define N2 2048
#define C1 256
#define C2 512
#define CO 768   // C1 + C2
#define CCH 4    // channels per interp block

// ws usage: nn_idx (B*N1*3 ints) + nn_w (B*N1*3 floats) = 1.5 MB (R0-proven).

// ---------------------------------------------------------------------------
// Kernel 1: VERBATIM from the R0 submission that PASSED (absmax 0.0156).
// Not one token changed. Single-variable bisection: only interp differs
// this round.
// ---------------------------------------------------------------------------
__global__ __launch_bounds__(256) void knn_kernel(
    const float* __restrict__ qxyz,   // (B, 3, N1)
    const float* __restrict__ kxyz,   // (B, 3, N2)
    int*   __restrict__ nn_idx,       // (B*N1*3)
    float* __restrict__ nn_w)         // (B*N1*3)
{
    __shared__ float skx[N2], sky[N2], skz[N2], skk[N2];
    const int b    = blockIdx.x >> 5;   // 32 tiles of 256 points per batch
    const int tile = blockIdx.x & 31;
    const int tid  = threadIdx.x;

    const float* kb = kxyz + (size_t)b * 3 * N2;
    for (int j = tid; j < N2; j += 256) {
        float x = kb[j], y = kb[N2 + j], z = kb[2 * N2 + j];
        skx[j] = x; sky[j] = y; skz[j] = z;
        skk[j] = __fadd_rn(__fadd_rn(__fmul_rn(x, x), __fmul_rn(y, y)),
                           __fmul_rn(z, z));
    }
    __syncthreads();

    const int n = tile * 256 + tid;
    const float* qb = qxyz + (size_t)b * 3 * N1;
    const float qx = qb[n], qy = qb[N1 + n], qz = qb[2 * N1 + n];
    const float qq = __fadd_rn(__fadd_rn(__fmul_rn(qx, qx), __fmul_rn(qy, qy)),
                               __fmul_rn(qz, qz));

    float b0 = 3.4e38f, b1 = 3.4e38f, b2 = 3.4e38f;
    int   i0 = 0, i1 = 0, i2 = 0;

    #pragma unroll 4
    for (int j = 0; j < N2; ++j) {
        float dot = fmaf(skz[j], qz, fmaf(sky[j], qy, __fmul_rn(skx[j], qx)));
        float d2  = __fsub_rn(__fadd_rn(qq, skk[j]), __fmul_rn(2.0f, dot));
        if (d2 < b2) {                       // rare: exec-mask skips most iters
            bool c0 = d2 < b0, c1 = d2 < b1;
            b2 = c1 ? b1 : d2;               i2 = c1 ? i1 : j;
            b1 = c0 ? b0 : (c1 ? d2 : b1);   i1 = c0 ? i0 : (c1 ? j : i1);
            b0 = c0 ? d2 : b0;               i0 = c0 ? j  : i0;
        }
    }

    // weights: mirror reference op order
    float d0f = fmaxf(b0, 1e-10f), d1f = fmaxf(b1, 1e-10f), d2f = fmaxf(b2, 1e-10f);
    float v0 = __fdiv_rn(1.0f, d0f), v1 = __fdiv_rn(1.0f, d1f), v2 = __fdiv_rn(1.0f, d2f);
    float s  = __fadd_rn(__fadd_rn(v0, v1), v2);
    float w0 = __fdiv_rn(v0, s), w1 = __fdiv_rn(v1, s), w2 = __fdiv_rn(v2, s);

    const int p = (b * N1 + n) * 3;
    nn_idx[p] = i0; nn_idx[p + 1] = i1; nn_idx[p + 2] = i2;
    nn_w[p]   = w0; nn_w[p + 1]  = w1; nn_w[p + 2]  = w2;
}

// ---------------------------------------------------------------------------
// Kernel 2 (THE one changed component): LDS-staged interp. Block = (batch,
// 4-channel group). Stage 4 channels x N2 keys into LDS padded [j][5]
// (stride-5 -> conflict-light). Random per-lane gathers hit LDS instead of
// splitting into 64 L2 lines per wave instruction (R1-measured 175us cause).
// kfeat read exactly once, coalesced; out writes coalesced. Per-element
// math is identical to R0's interp_kernel: fmaf(w2,f2,fmaf(w1,f1,mul(w0,f0)))
// on f_k = kfeat[b][c][i_k].
// ---------------------------------------------------------------------------
__global__ __launch_bounds__(256) void interp3(
    const float* __restrict__ kfeat,  // (B, C2, N2)
    const int*   __restrict__ nn_idx,
    const float* __restrict__ nn_w,
    float* __restrict__ out)          // (B, CO, N1)
{
    __shared__ float skf[N2 * 5];      // 40 KB
    const int b     = blockIdx.x & 7;       // XCD-pinned batch
    const int cg    = blockIdx.x >> 3;      // 0..127
    const int cbase = cg * CCH;
    const int tid   = threadIdx.x;

    const float* kf = kfeat + (size_t)b * C2 * N2 + (size_t)cbase * N2;
    for (int idx = tid; idx < CCH * N2; idx += 256) {
        int c = idx >> 11, j = idx & (N2 - 1);
        skf[j * 5 + c] = kf[(size_t)c * N2 + j];
    }
    __syncthreads();

    const int*   ib = nn_idx + (size_t)b * N1 * 3;
    const float* wb = nn_w   + (size_t)b * N1 * 3;
    float* ob = out + (size_t)b * CO * N1;

    #pragma unroll 4
    for (int t = 0; t < N1 / 256; ++t) {
        const int n = t * 256 + tid;
        const int   i0 = ib[n * 3], i1 = ib[n * 3 + 1], i2 = ib[n * 3 + 2];
        const float w0 = wb[n * 3], w1 = wb[n * 3 + 1], w2 = wb[n * 3 + 2];
        #pragma unroll
        for (int c = 0; c < CCH; ++c) {
            float f0 = skf[i0 * 5 + c], f1 = skf[i1 * 5 + c], f2 = skf[i2 * 5 + c];
            ob[(size_t)(cbase + c) * N1 + n] =
                fmaf(w2, f2, fmaf(w1, f1, __fmul_rn(w0, f0)));
        }
    }
}

// ---------------------------------------------------------------------------
// Kernel 3: VERBATIM from the R0 submission that PASSED.
// ---------------------------------------------------------------------------
__global__ __launch_bounds__(256) void copy_kernel(
    const float* __restrict__ qfeat,  // (B, C1, N1)
    float* __restrict__ out)          // (B, CO, N1)
{
    // 2048 blocks per batch, each thread moves one float4
    const int b = blockIdx.x >> 11;
    const size_t r = ((size_t)(blockIdx.x & 2047)) * 256 + threadIdx.x; // float4 idx
    const float4* src = (const float4*)(qfeat + (size_t)b * C1 * N1);
    float4* dst = (float4*)(out + (size_t)b * CO * N1 + (size_t)C2 * N1);
    dst[r] = src[r];
}

extern "C" void kernel_launch(void* const* d_in, const int* in_sizes, int n_in,
                              void* d_out, int out_size, void* d_ws, size_t ws_size,
                              hipStream_t stream) {
    const float* qxyz  = (const float*)d_in[0];
    const float* kxyz  = (const float*)d_in[1];
    const float* qfeat = (const float*)d_in[2];
    const float* kfeat = (const float*)d_in[3];
    float* out = (float*)d_out;

    int*   nn_idx = (int*)d_ws;                              // 3*B*N1 ints
    float* nn_w   = (float*)d_ws + (size_t)3 * NB * N1;      // 3*B*N1 floats

    knn_kernel<<<NB * (N1 / 256), 256, 0, stream>>>(qxyz, kxyz, nn_idx, nn_w);
    interp3<<<NB * (C2 / CCH), 256, 0, stream>>>(kfeat, nn_idx, nn_w, out);
    copy_kernel<<<NB * 2048, 256, 0, stream>>>(qfeat, out);
}

// Round 6
// 181.648 us; speedup vs baseline: 1.9926x; 1.2713x over previous
//
#include <hip/hip_runtime.h>

#define NB 8
#define N1 8192
#define N2 2048
#define C1 256
#define C2 512
#define CO 768   // C1 + C2
#define CCH 4    // channels per interp block

// ws usage: nn_idx (B*N1*3 ints) + nn_w (B*N1*3 floats) = 1.5 MB (validated).

// ---------------------------------------------------------------------------
// Kernel 1: R0/R5-validated KNN semantics. Four scalar LDS arrays (same
// layout, now 16B-aligned), same staging, same ascending scan, same branchy
// insertion body, same weight math, same stores. ONLY change: keys are read
// from the SAME arrays four-at-a-time as float4 (broadcast ds_read_b128)
// into named registers with a 2-group prefetch pipeline, so the ~120cyc LDS
// latency overlaps the previous group's compute at 1 wave/SIMD.
// R4 lesson: do NOT restructure the d2 expression tree or the branchy
// use-structure — near-tie neighbor selection flips with 1-ulp d2 changes.
// ---------------------------------------------------------------------------
__global__ __launch_bounds__(256) void knn_kernel(
    const float* __restrict__ qxyz,   // (B, 3, N1)
    const float* __restrict__ kxyz,   // (B, 3, N2)
    int*   __restrict__ nn_idx,       // (B*N1*3)
    float* __restrict__ nn_w)         // (B*N1*3)
{
    __shared__ __align__(16) float skx[N2];
    __shared__ __align__(16) float sky[N2];
    __shared__ __align__(16) float skz[N2];
    __shared__ __align__(16) float skk[N2];
    const int b    = blockIdx.x >> 5;   // 32 tiles of 256 points per batch
    const int tile = blockIdx.x & 31;
    const int tid  = threadIdx.x;

    const float* kb = kxyz + (size_t)b * 3 * N2;
    for (int j = tid; j < N2; j += 256) {
        float x = kb[j], y = kb[N2 + j], z = kb[2 * N2 + j];
        skx[j] = x; sky[j] = y; skz[j] = z;
        skk[j] = __fadd_rn(__fadd_rn(__fmul_rn(x, x), __fmul_rn(y, y)),
                           __fmul_rn(z, z));
    }
    __syncthreads();

    const int n = tile * 256 + tid;
    const float* qb = qxyz + (size_t)b * 3 * N1;
    const float qx = qb[n], qy = qb[N1 + n], qz = qb[2 * N1 + n];
    const float qq = __fadd_rn(__fadd_rn(__fmul_rn(qx, qx), __fmul_rn(qy, qy)),
                               __fmul_rn(qz, qz));

    float b0 = 3.4e38f, b1 = 3.4e38f, b2 = 3.4e38f;
    int   i0 = 0, i1 = 0, i2 = 0;

    // VERBATIM R0 per-key body (expression tree + branchy structure intact).
#define PROC(X, Y, Z, KK, J) do {                                          \
        float dot = fmaf((Z), qz, fmaf((Y), qy, __fmul_rn((X), qx)));      \
        float d2  = __fsub_rn(__fadd_rn(qq, (KK)), __fmul_rn(2.0f, dot));  \
        if (d2 < b2) {                                                     \
            bool c0 = d2 < b0, c1 = d2 < b1;                               \
            b2 = c1 ? b1 : d2;               i2 = c1 ? i1 : (J);           \
            b1 = c0 ? b0 : (c1 ? d2 : b1);   i1 = c0 ? i0 : (c1 ? (J) : i1); \
            b0 = c0 ? d2 : b0;               i0 = c0 ? (J) : i0;           \
        }                                                                  \
    } while (0)

    // 2-deep group prefetch: groups jb (a*), jb+4 (b*) live; load jb+8.
    float4 ax = *(const float4*)&skx[0], ay = *(const float4*)&sky[0],
           az = *(const float4*)&skz[0], ak = *(const float4*)&skk[0];
    float4 gx = *(const float4*)&skx[4], gy = *(const float4*)&sky[4],
           gz = *(const float4*)&skz[4], gk = *(const float4*)&skk[4];

    #pragma unroll 2
    for (int jb = 0; jb < N2; jb += 4) {
        const int jp = (jb + 8) & (N2 - 1);   // wraps at tail; values unused
        float4 nx = *(const float4*)&skx[jp];
        float4 ny = *(const float4*)&sky[jp];
        float4 nz = *(const float4*)&skz[jp];
        float4 nk = *(const float4*)&skk[jp];
        PROC(ax.x, ay.x, az.x, ak.x, jb + 0);
        PROC(ax.y, ay.y, az.y, ak.y, jb + 1);
        PROC(ax.z, ay.z, az.z, ak.z, jb + 2);
        PROC(ax.w, ay.w, az.w, ak.w, jb + 3);
        ax = gx; ay = gy; az = gz; ak = gk;
        gx = nx; gy = ny; gz = nz; gk = nk;
    }
#undef PROC

    // weights: mirror reference op order (verbatim R0)
    float d0f = fmaxf(b0, 1e-10f), d1f = fmaxf(b1, 1e-10f), d2f = fmaxf(b2, 1e-10f);
    float v0 = __fdiv_rn(1.0f, d0f), v1 = __fdiv_rn(1.0f, d1f), v2 = __fdiv_rn(1.0f, d2f);
    float s  = __fadd_rn(__fadd_rn(v0, v1), v2);
    float w0 = __fdiv_rn(v0, s), w1 = __fdiv_rn(v1, s), w2 = __fdiv_rn(v2, s);

    const int p = (b * N1 + n) * 3;
    nn_idx[p] = i0; nn_idx[p + 1] = i1; nn_idx[p + 2] = i2;
    nn_w[p]   = w0; nn_w[p + 1]  = w1; nn_w[p + 2]  = w2;
}

// ---------------------------------------------------------------------------
// Kernel 2: VERBATIM from R5 (validated). LDS-staged gather interp.
// ---------------------------------------------------------------------------
__global__ __launch_bounds__(256) void interp3(
    const float* __restrict__ kfeat,  // (B, C2, N2)
    const int*   __restrict__ nn_idx,
    const float* __restrict__ nn_w,
    float* __restrict__ out)          // (B, CO, N1)
{
    __shared__ float skf[N2 * 5];      // 40 KB
    const int b     = blockIdx.x & 7;       // XCD-pinned batch
    const int cg    = blockIdx.x >> 3;      // 0..127
    const int cbase = cg * CCH;
    const int tid   = threadIdx.x;

    const float* kf = kfeat + (size_t)b * C2 * N2 + (size_t)cbase * N2;
    for (int idx = tid; idx < CCH * N2; idx += 256) {
        int c = idx >> 11, j = idx & (N2 - 1);
        skf[j * 5 + c] = kf[(size_t)c * N2 + j];
    }
    __syncthreads();

    const int*   ib = nn_idx + (size_t)b * N1 * 3;
    const float* wb = nn_w   + (size_t)b * N1 * 3;
    float* ob = out + (size_t)b * CO * N1;

    #pragma unroll 4
    for (int t = 0; t < N1 / 256; ++t) {
        const int n = t * 256 + tid;
        const int   i0 = ib[n * 3], i1 = ib[n * 3 + 1], i2 = ib[n * 3 + 2];
        const float w0 = wb[n * 3], w1 = wb[n * 3 + 1], w2 = wb[n * 3 + 2];
        #pragma unroll
        for (int c = 0; c < CCH; ++c) {
            float f0 = skf[i0 * 5 + c], f1 = skf[i1 * 5 + c], f2 = skf[i2 * 5 + c];
            ob[(size_t)(cbase + c) * N1 + n] =
                fmaf(w2, f2, fmaf(w1, f1, __fmul_rn(w0, f0)));
        }
    }
}

// ---------------------------------------------------------------------------
// Kernel 3: VERBATIM from R0/R5 (validated). float4 stream copy.
// ---------------------------------------------------------------------------
__global__ __launch_bounds__(256) void copy_kernel(
    const float* __restrict__ qfeat,  // (B, C1, N1)
    float* __restrict__ out)          // (B, CO, N1)
{
    const int b = blockIdx.x >> 11;
    const size_t r = ((size_t)(blockIdx.x & 2047)) * 256 + threadIdx.x;
    const float4* src = (const float4*)(qfeat + (size_t)b * C1 * N1);
    float4* dst = (float4*)(out + (size_t)b * CO * N1 + (size_t)C2 * N1);
    dst[r] = src[r];
}

extern "C" void kernel_launch(void* const* d_in, const int* in_sizes, int n_in,
                              void* d_out, int out_size, void* d_ws, size_t ws_size,
                              hipStream_t stream) {
    const float* qxyz  = (const float*)d_in[0];
    const float* kxyz  = (const float*)d_in[1];
    const float* qfeat = (const float*)d_in[2];
    const float* kfeat = (const float*)d_in[3];
    float* out = (float*)d_out;

    int*   nn_idx = (int*)d_ws;                              // 3*B*N1 ints
    float* nn_w   = (float*)d_ws + (size_t)3 * NB * N1;      // 3*B*N1 floats

    knn_kernel<<<NB * (N1 / 256), 256, 0, stream>>>(qxyz, kxyz, nn_idx, nn_w);
    interp3<<<NB * (C2 / CCH), 256, 0, stream>>>(kfeat, nn_idx, nn_w, out);
    copy_kernel<<<NB * 2048, 256, 0, stream>>>(qfeat, out);
}

// Round 8
// 113.493 us; speedup vs baseline: 3.1892x; 1.6005x over previous
//
#include <hip/hip_runtime.h>

#define NB 8
#define N1 8192
#define N2 2048
#define C1 256
#define C2 512
#define CO 768   // C1 + C2
#define CCH 4    // channels per interp block

// ws usage: nn_idx (B*N1*3 ints) + nn_w (B*N1*3 floats) = 1.5 MB (validated).

// ---------------------------------------------------------------------------
// ASM-PINNED arithmetic, v2. R7 evidence: pinning a NO-fma dot gave absmax
// 0.2886 (3rd-neighbor membership flips vs numpy); all passing rounds used
// an fma-chain dot in source (matching CPU BLAS/XLA's fma dot). So pin:
//   nrm2 = (x*x + y*y) + z*z            (stepwise rn — as in passing rounds)
//   dot  = fma(z,qz, fma(y,qy, x*qx))   (fma chain — as in passing rounds)
//   d2   = (qq + kk) - 2*dot            (stepwise rn)
// Now bit-stable under ANY loop restructuring.
// ---------------------------------------------------------------------------
#define NRM2(X, Y, Z) ({                                                   \
    float _s, _t;                                                          \
    asm("v_mul_f32 %0, %2, %2\n\t"                                         \
        "v_mul_f32 %1, %3, %3\n\t"                                         \
        "v_add_f32 %0, %0, %1\n\t"                                         \
        "v_mul_f32 %1, %4, %4\n\t"                                         \
        "v_add_f32 %0, %0, %1"                                             \
        : "=&v"(_s), "=&v"(_t) : "v"(X), "v"(Y), "v"(Z));                  \
    _s; })

#define D2PIN(QX, QY, QZ, QQ, X, Y, Z, KK) ({                              \
    float _d, _t;                                                          \
    asm("v_mul_f32 %0, %2, %5\n\t"        /* qx*kx                  */     \
        "v_fma_f32 %0, %3, %6, %0\n\t"    /* + qy*ky (single-round) */     \
        "v_fma_f32 %0, %4, %7, %0\n\t"    /* + qz*kz (single-round) */     \
        "v_add_f32 %1, %8, %9\n\t"        /* qq+kk                  */     \
        "v_mul_f32 %0, 2.0, %0\n\t"       /* 2*dot                  */     \
        "v_sub_f32 %0, %1, %0"            /* d2                     */     \
        : "=&v"(_d), "=&v"(_t)                                             \
        : "v"(QX), "v"(QY), "v"(QZ), "v"(X), "v"(Y), "v"(Z),               \
          "v"(QQ), "v"(KK));                                               \
    _d; })

// ---------------------------------------------------------------------------
// 4-wave KNN (structure identical to R7; only D2PIN changed): block = 64
// queries; all waves stage all 2048 keys, wave w scans keys [w*512,(w+1)*512)
// ascending (lane = query). Chunk-local sorted top-3 merged by tid<64 in
// (chunk asc, rank asc) order with strict-< => identical selection to a
// single ascending scan == jax.lax.top_k (lowest index wins ties).
// ---------------------------------------------------------------------------
__global__ __launch_bounds__(256, 4) void knn_fused(
    const float* __restrict__ qxyz,   // (B, 3, N1)
    const float* __restrict__ kxyz,   // (B, 3, N2)
    int*   __restrict__ nn_idx,       // (B*N1*3)
    float* __restrict__ nn_w)         // (B*N1*3)
{
    __shared__ __align__(16) float skx[N2];
    __shared__ __align__(16) float sky[N2];
    __shared__ __align__(16) float skz[N2];
    __shared__ __align__(16) float skk[N2];
    __shared__ float pd[4][64][3];
    __shared__ int   pi[4][64][3];

    const int b   = blockIdx.x >> 7;        // 128 tiles of 64 queries
    const int n0  = (blockIdx.x & 127) * 64;
    const int tid = threadIdx.x;
    const int w   = tid >> 6, lane = tid & 63;

    const float* kb = kxyz + (size_t)b * 3 * N2;
    for (int j = tid; j < N2; j += 256) {
        float x = kb[j], y = kb[N2 + j], z = kb[2 * N2 + j];
        skx[j] = x; sky[j] = y; skz[j] = z;
        skk[j] = NRM2(x, y, z);
    }
    __syncthreads();

    const int n = n0 + lane;
    const float* qb = qxyz + (size_t)b * 3 * N1;
    const float qx = qb[n], qy = qb[N1 + n], qz = qb[2 * N1 + n];
    const float qq = NRM2(qx, qy, qz);

    float b0 = 3.4e38f, b1 = 3.4e38f, b2 = 3.4e38f;
    int   i0 = 0, i1 = 0, i2 = 0;

#define PROC(X, Y, Z, KK, J) do {                                          \
        float d2 = D2PIN(qx, qy, qz, qq, (X), (Y), (Z), (KK));             \
        if (d2 < b2) {                                                     \
            bool c0 = d2 < b0, c1 = d2 < b1;                               \
            b2 = c1 ? b1 : d2;               i2 = c1 ? i1 : (J);           \
            b1 = c0 ? b0 : (c1 ? d2 : b1);   i1 = c0 ? i0 : (c1 ? (J) : i1); \
            b0 = c0 ? d2 : b0;               i0 = c0 ? (J) : i0;           \
        }                                                                  \
    } while (0)

    const int jlo = w * (N2 / 4), jhi = jlo + (N2 / 4);
    #pragma unroll 4
    for (int jb = jlo; jb < jhi; jb += 4) {
        float4 x4 = *(const float4*)&skx[jb];
        float4 y4 = *(const float4*)&sky[jb];
        float4 z4 = *(const float4*)&skz[jb];
        float4 k4 = *(const float4*)&skk[jb];
        PROC(x4.x, y4.x, z4.x, k4.x, jb + 0);
        PROC(x4.y, y4.y, z4.y, k4.y, jb + 1);
        PROC(x4.z, y4.z, z4.z, k4.z, jb + 2);
        PROC(x4.w, y4.w, z4.w, k4.w, jb + 3);
    }
#undef PROC

    pd[w][lane][0] = b0; pd[w][lane][1] = b1; pd[w][lane][2] = b2;
    pi[w][lane][0] = i0; pi[w][lane][1] = i1; pi[w][lane][2] = i2;
    __syncthreads();

    if (tid < 64) {
        float m0 = 3.4e38f, m1 = 3.4e38f, m2 = 3.4e38f;
        int   j0 = 0, j1 = 0, j2 = 0;
        #pragma unroll
        for (int c = 0; c < 4; ++c) {
            #pragma unroll
            for (int s = 0; s < 3; ++s) {
                float d = pd[c][tid][s];
                int   i = pi[c][tid][s];
                if (d < m2) {
                    bool c0 = d < m0, c1 = d < m1;
                    m2 = c1 ? m1 : d;                j2 = c1 ? j1 : i;
                    m1 = c0 ? m0 : (c1 ? d : m1);    j1 = c0 ? j0 : (c1 ? i : j1);
                    m0 = c0 ? d : m0;                j0 = c0 ? i  : j0;
                }
            }
        }
        // weights: mirror reference op order (divides are exact-IEEE, safe)
        float d0f = fmaxf(m0, 1e-10f), d1f = fmaxf(m1, 1e-10f), d2f = fmaxf(m2, 1e-10f);
        float v0 = __fdiv_rn(1.0f, d0f), v1 = __fdiv_rn(1.0f, d1f), v2 = __fdiv_rn(1.0f, d2f);
        float s  = __fadd_rn(__fadd_rn(v0, v1), v2);
        const size_t p = ((size_t)b * N1 + n0 + tid) * 3;
        nn_idx[p] = j0; nn_idx[p + 1] = j1; nn_idx[p + 2] = j2;
        nn_w[p]   = __fdiv_rn(v0, s);
        nn_w[p+1] = __fdiv_rn(v1, s);
        nn_w[p+2] = __fdiv_rn(v2, s);
    }
}

// ---------------------------------------------------------------------------
// Kernel 2: VERBATIM from R5/R6 (validated). LDS-staged gather interp.
// ---------------------------------------------------------------------------
__global__ __launch_bounds__(256) void interp3(
    const float* __restrict__ kfeat,  // (B, C2, N2)
    const int*   __restrict__ nn_idx,
    const float* __restrict__ nn_w,
    float* __restrict__ out)          // (B, CO, N1)
{
    __shared__ float skf[N2 * 5];      // 40 KB
    const int b     = blockIdx.x & 7;       // XCD-pinned batch
    const int cg    = blockIdx.x >> 3;      // 0..127
    const int cbase = cg * CCH;
    const int tid   = threadIdx.x;

    const float* kf = kfeat + (size_t)b * C2 * N2 + (size_t)cbase * N2;
    for (int idx = tid; idx < CCH * N2; idx += 256) {
        int c = idx >> 11, j = idx & (N2 - 1);
        skf[j * 5 + c] = kf[(size_t)c * N2 + j];
    }
    __syncthreads();

    const int*   ib = nn_idx + (size_t)b * N1 * 3;
    const float* wb = nn_w   + (size_t)b * N1 * 3;
    float* ob = out + (size_t)b * CO * N1;

    #pragma unroll 4
    for (int t = 0; t < N1 / 256; ++t) {
        const int n = t * 256 + tid;
        const int   i0 = ib[n * 3], i1 = ib[n * 3 + 1], i2 = ib[n * 3 + 2];
        const float w0 = wb[n * 3], w1 = wb[n * 3 + 1], w2 = wb[n * 3 + 2];
        #pragma unroll
        for (int c = 0; c < CCH; ++c) {
            float f0 = skf[i0 * 5 + c], f1 = skf[i1 * 5 + c], f2 = skf[i2 * 5 + c];
            ob[(size_t)(cbase + c) * N1 + n] =
                fmaf(w2, f2, fmaf(w1, f1, __fmul_rn(w0, f0)));
        }
    }
}

// ---------------------------------------------------------------------------
// Kernel 3: VERBATIM from R0/R5/R6 (validated). float4 stream copy.
// ---------------------------------------------------------------------------
__global__ __launch_bounds__(256) void copy_kernel(
    const float* __restrict__ qfeat,  // (B, C1, N1)
    float* __restrict__ out)          // (B, CO, N1)
{
    const int b = blockIdx.x >> 11;
    const size_t r = ((size_t)(blockIdx.x & 2047)) * 256 + threadIdx.x;
    const float4* src = (const float4*)(qfeat + (size_t)b * C1 * N1);
    float4* dst = (float4*)(out + (size_t)b * CO * N1 + (size_t)C2 * N1);
    dst[r] = src[r];
}

extern "C" void kernel_launch(void* const* d_in, const int* in_sizes, int n_in,
                              void* d_out, int out_size, void* d_ws, size_t ws_size,
                              hipStream_t stream) {
    const float* qxyz  = (const float*)d_in[0];
    const float* kxyz  = (const float*)d_in[1];
    const float* qfeat = (const float*)d_in[2];
    const float* kfeat = (const float*)d_in[3];
    float* out = (float*)d_out;

    int*   nn_idx = (int*)d_ws;                              // 3*B*N1 ints
    float* nn_w   = (float*)d_ws + (size_t)3 * NB * N1;      // 3*B*N1 floats

    knn_fused<<<NB * (N1 / 64), 256, 0, stream>>>(qxyz, kxyz, nn_idx, nn_w);
    interp3<<<NB * (C2 / CCH), 256, 0, stream>>>(kfeat, nn_idx, nn_w, out);
    copy_kernel<<<NB * 2048, 256, 0, stream>>>(qfeat, out);
}